// Round 12
// baseline (208.603 us; speedup 1.0000x reference)
//
#include <hip/hip_runtime.h>
#include <math.h>

#define BATCH   2
#define T_SEQ   2048
#define DMODEL  1024
#define NHEAD   16
#define HDIM    64

typedef short s16x8 __attribute__((ext_vector_type(8)));
typedef unsigned short u16x8 __attribute__((ext_vector_type(8)));
typedef unsigned short u16x4 __attribute__((ext_vector_type(4)));
typedef unsigned int u32x2 __attribute__((ext_vector_type(2)));
typedef float f32x4 __attribute__((ext_vector_type(4)));

typedef const unsigned int __attribute__((address_space(1))) GUI;
typedef unsigned int __attribute__((address_space(3))) LUI;

// fp32 -> bf16 round-to-nearest-even (bit pattern)
static __device__ __forceinline__ unsigned short f2bf(float f) {
    unsigned int u = __float_as_uint(f);
    u += 0x7fffu + ((u >> 16) & 1u);
    return (unsigned short)(u >> 16);
}

// two fp32 -> packed bf16x2 (round-half-up) via one v_perm_b32
static __device__ __forceinline__ unsigned int f2bf_pack2(float a, float b) {
    const unsigned int ua = __float_as_uint(a) + 0x8000u;
    const unsigned int ub = __float_as_uint(b) + 0x8000u;
    return __builtin_amdgcn_perm(ub, ua, 0x07060302u);
}

// ---------------------------------------------------------------------------
// Fused prep: blocks 0..2047 convert x -> bf16; 2048..2815 transpose Wqkv;
// 2816..3071 transpose Wout; 3072..3327 build RoPE table TRANSPOSED:
// tabT[d2][t] = (cos(t*f_d2), sin(t*f_d2)) as float2, f_d2 = 10000^(-d2/32).
// t-contiguous so epilogues can read 4 entries with two float4 loads.
// ---------------------------------------------------------------------------
__global__ __launch_bounds__(256) void prep_fused(
    const float* __restrict__ x, const float* __restrict__ Wqkv,
    const float* __restrict__ Wout,
    unsigned short* __restrict__ xb, unsigned short* __restrict__ Wqkv_t,
    unsigned short* __restrict__ Wout_t, float2* __restrict__ rope_tab)
{
    __shared__ unsigned short tile[64][68];
    const int bid = blockIdx.x;
    const int tid = threadIdx.x;

    if (bid < 2048) {
        const int i = bid * 256 + tid;
        const float4 a = ((const float4*)x)[2 * i];
        const float4 b = ((const float4*)x)[2 * i + 1];
        u16x8 r;
        r[0] = f2bf(a.x); r[1] = f2bf(a.y); r[2] = f2bf(a.z); r[3] = f2bf(a.w);
        r[4] = f2bf(b.x); r[5] = f2bf(b.y); r[6] = f2bf(b.z); r[7] = f2bf(b.w);
        ((u16x8*)xb)[i] = r;
        return;
    }
    if (bid >= 3072) {
        // RoPE table: 65536 entries = 256 blocks x 256 threads, [d2][t] layout
        const int idx = (bid - 3072) * 256 + tid;
        const int d2 = idx >> 11;          // 0..31
        const int t  = idx & 2047;
        const float inv_freq = exp2f(-(float)d2 * 0.41524101186092029f); // log2(1e4)/32
        float s, c;
        sincosf((float)t * inv_freq, &s, &c);
        rope_tab[d2 * 2048 + t] = make_float2(c, s);
        return;
    }

    const float* src;
    unsigned short* dst;
    int R, C, bx, by;
    if (bid < 2816) {
        const int id = bid - 2048;
        src = Wqkv; dst = Wqkv_t; R = DMODEL; C = 3 * DMODEL;
        bx = id % 48; by = id / 48;
    } else {
        const int id = bid - 2816;
        src = Wout; dst = Wout_t; R = DMODEL; C = DMODEL;
        bx = id % 16; by = id / 16;
    }
    const int tc0 = bx * 64;
    const int tr0 = by * 64;
    const int tx = tid & 63;
    const int ty = tid >> 6;
#pragma unroll
    for (int i = 0; i < 16; i++) {
        const int rr = i * 4 + ty;
        tile[tx][rr] = f2bf(src[(size_t)(tr0 + rr) * C + tc0 + tx]);
    }
    __syncthreads();
#pragma unroll
    for (int i = 0; i < 16; i++) {
        const int cc = i * 4 + ty;
        dst[(size_t)(tc0 + cc) * R + tr0 + tx] = tile[cc][tx];
    }
}

// ---------------------------------------------------------------------------
// Shared MFMA GEMM main loop, DOUBLE-BUFFERED, one barrier per K-slice.
// ---------------------------------------------------------------------------
__device__ __forceinline__ void mfma_gemm_loop_db(
    const unsigned short* __restrict__ A, const unsigned short* __restrict__ Bt,
    unsigned short* As, unsigned short* Bs,
    int m0, int n0, int K, f32x4 acc[4][4])
{
    const int tid  = threadIdx.x;
    const int wave = tid >> 6;
    const int lane = tid & 63;
    const int quad = lane >> 4;
    const int lc   = lane & 15;
    const int wr   = (wave >> 1) * 64;
    const int wc   = (wave & 1) * 64;

    const int c0    = wave * 2;
    const int srow0 = c0 * 16 + (lane >> 2);
    const int scol  = (lane & 3) * 8;

#pragma unroll
    for (int i = 0; i < 4; i++)
#pragma unroll
        for (int j = 0; j < 4; j++)
            acc[i][j] = (f32x4){0.f, 0.f, 0.f, 0.f};

    auto stage = [&](int kt, int buf) {
        const unsigned short* ga0 = A + (size_t)(m0 + srow0) * K + kt + scol;
        const unsigned short* ga1 = A + (size_t)(m0 + srow0 + 16) * K + kt + scol;
        const unsigned short* gb0 = Bt + (size_t)(n0 + srow0) * K + kt + scol;
        const unsigned short* gb1 = Bt + (size_t)(n0 + srow0 + 16) * K + kt + scol;
        unsigned short* as = As + buf * 4096;
        unsigned short* bs = Bs + buf * 4096;
        __builtin_amdgcn_global_load_lds((GUI*)ga0, (LUI*)(as + c0 * 512 + lane * 8), 16, 0, 0);
        __builtin_amdgcn_global_load_lds((GUI*)ga1, (LUI*)(as + (c0 + 1) * 512 + lane * 8), 16, 0, 0);
        __builtin_amdgcn_global_load_lds((GUI*)gb0, (LUI*)(bs + c0 * 512 + lane * 8), 16, 0, 0);
        __builtin_amdgcn_global_load_lds((GUI*)gb1, (LUI*)(bs + (c0 + 1) * 512 + lane * 8), 16, 0, 0);
    };

    stage(0, 0);
    const int nit = K >> 5;
    for (int it = 0; it < nit; ++it) {
        __syncthreads();
        if (it + 1 < nit) stage((it + 1) << 5, (it + 1) & 1);

        const unsigned short* as = As + (it & 1) * 4096;
        const unsigned short* bs = Bs + (it & 1) * 4096;
        s16x8 a[4], b[4];
#pragma unroll
        for (int mt = 0; mt < 4; mt++)
            a[mt] = *(const s16x8*)(as + (wr + mt * 16 + lc) * 32 + quad * 8);
#pragma unroll
        for (int nb = 0; nb < 4; nb++)
            b[nb] = *(const s16x8*)(bs + (wc + nb * 16 + lc) * 32 + quad * 8);
#pragma unroll
        for (int mt = 0; mt < 4; mt++)
#pragma unroll
            for (int nb = 0; nb < 4; nb++)
                acc[mt][nb] = __builtin_amdgcn_mfma_f32_16x16x32_bf16(a[mt], b[nb], acc[mt][nb], 0, 0, 0);
    }
}

// ---------------------------------------------------------------------------
// QKV GEMM (bf16 MFMA, dbuf) + RoPE (tabT lookup) + Q-scale + pack.
// XCD-affine 1-D grid 768 (xcd strip = 3 n-blocks, m streams, n-subs inner).
// Output layouts:  Q -> (B,H,64,T) TRANSPOSED (coalesced u32x2 stores along t)
//                  V -> (B,H,64,T) TRANSPOSED (same path)
//                  K -> (B,H,T,64) via per-wave LDS transpose -> coalesced
//                       u16x8 row stores (K must stay t-major for attn's
//                       global_load_lds staging).
// Rationale (r11 counters): scattered 2-byte epilogue stores caused ~24 MB of
// HBM RMW line fills (FETCH 37.5 vs 14 compulsory) and dominated VALU.
// ---------------------------------------------------------------------------
__global__ __launch_bounds__(256) void gemm_qkv_rope_mfma(
    const unsigned short* __restrict__ xb, const unsigned short* __restrict__ Wt,
    const float* __restrict__ tabT,        // [32][2048] float2 as flat float
    unsigned short* __restrict__ Qt, unsigned short* __restrict__ Kb,
    unsigned short* __restrict__ Vt)
{
    // As(2 buf)=16 KB + Bs(2 buf)=16 KB + 4 KB pad = 36 KB; K-part epilogue
    // reuses it as 4 per-wave [64][72] transpose tiles (4*9 KB).
    __shared__ __align__(16) unsigned short SH[18432];
    unsigned short* As = SH;
    unsigned short* Bs = SH + 8192;

    const int id  = blockIdx.x;               // 0..767
    const int s   = id >> 3;                  // 0..95
    const int n0  = ((id & 7) * 3 + (s % 3)) * 128;
    const int m0  = (s / 3) * 128;
    f32x4 acc[4][4];
    mfma_gemm_loop_db(xb, Wt, As, Bs, m0, n0, DMODEL, acc);

    const int lane = threadIdx.x & 63;
    const int wave = threadIdx.x >> 6;
    const int quad = lane >> 4;
    const int lc   = lane & 15;
    const int wr   = (wave >> 1) * 64;
    const int wc   = (wave & 1) * 64;

    const int n_base = n0 + wc;
    const int part = n_base >> 10;       // 0=q 1=k 2=v, uniform per block
    const float qscale = 0.125f * 1.4426950408889634f;  // 1/sqrt(64) * log2(e)
    const float ssign = (lc & 1) ? 1.f : -1.f;

    if (part != 1) {
        // ---- Q and V: d-major (B,H,64,T), u32x2 stores along t ----
        unsigned short* dst = (part == 0) ? Qt : Vt;
#pragma unroll
        for (int nb = 0; nb < 4; nb++) {
            const int n = n_base + nb * 16 + lc;
            const int h = (n >> 6) & 15;
            const int d = n & 63;
            const int d2 = d >> 1;
#pragma unroll
            for (int mt = 0; mt < 4; mt++) {
                const int mb = m0 + wr + mt * 16 + quad * 4;
                const int bb = mb >> 11, t = mb & 2047;
                f32x4 v = acc[mt][nb];
                if (part == 0) {
                    const float4 cs0 = *(const float4*)&tabT[d2 * 4096 + 2 * t];     // c0,s0,c1,s1
                    const float4 cs1 = *(const float4*)&tabT[d2 * 4096 + 2 * t + 4]; // c2,s2,c3,s3
                    float pr[4];
#pragma unroll
                    for (int r = 0; r < 4; r++) pr[r] = __shfl_xor(v[r], 1);
                    v[0] = fmaf(pr[0], ssign * cs0.y, v[0] * cs0.x) * qscale;
                    v[1] = fmaf(pr[1], ssign * cs0.w, v[1] * cs0.z) * qscale;
                    v[2] = fmaf(pr[2], ssign * cs1.y, v[2] * cs1.x) * qscale;
                    v[3] = fmaf(pr[3], ssign * cs1.w, v[3] * cs1.z) * qscale;
                }
                u32x2 pk;
                pk[0] = f2bf_pack2(v[0], v[1]);
                pk[1] = f2bf_pack2(v[2], v[3]);
                *(u32x2*)&dst[((size_t)((bb * NHEAD + h) * HDIM + d)) * T_SEQ + t] = pk;
            }
        }
    } else {
        // ---- K: RoPE then per-wave LDS transpose -> coalesced row stores ----
        __syncthreads();   // all waves done reading As/Bs (K-loop data)
        unsigned short* Ls = SH + wave * 4608;   // [64][72]
#pragma unroll
        for (int nb = 0; nb < 4; nb++) {
            const int n = n_base + nb * 16 + lc;
            const int d2 = (n & 63) >> 1;
#pragma unroll
            for (int mt = 0; mt < 4; mt++) {
                const int mb = m0 + wr + mt * 16 + quad * 4;
                const int t = mb & 2047;
                const float4 cs0 = *(const float4*)&tabT[d2 * 4096 + 2 * t];
                const float4 cs1 = *(const float4*)&tabT[d2 * 4096 + 2 * t + 4];
                f32x4 v = acc[mt][nb];
                float pr[4];
#pragma unroll
                for (int r = 0; r < 4; r++) pr[r] = __shfl_xor(v[r], 1);
                v[0] = fmaf(pr[0], ssign * cs0.y, v[0] * cs0.x);
                v[1] = fmaf(pr[1], ssign * cs0.w, v[1] * cs0.z);
                v[2] = fmaf(pr[2], ssign * cs1.y, v[2] * cs1.x);
                v[3] = fmaf(pr[3], ssign * cs1.w, v[3] * cs1.z);
#pragma unroll
                for (int r = 0; r < 4; r++)
                    Ls[(mt * 16 + quad * 4 + r) * 72 + nb * 16 + lc] = f2bf(v[r]);
            }
        }
        // wave-local readout: lane owns one output row (t), 64 d contiguous
        const int h  = (n_base >> 6) & 15;
        const int bb = (m0 + wr) >> 11;
        const int t  = ((m0 + wr) & 2047) + lane;
        unsigned short* krow = Kb + ((size_t)((bb * NHEAD + h) * T_SEQ + t)) * HDIM;
#pragma unroll
        for (int j = 0; j < 8; j++)
            *(u16x8*)(krow + j * 8) = *(const u16x8*)&Ls[lane * 72 + j * 8];
    }
}

// ---------------------------------------------------------------------------
// Out-proj GEMM (bf16 MFMA, dbuf): out[M,1024] fp32 = attnb x Wout_t^T.
// 1-D grid 256, XCD-affine: xcd = id&7 owns n-block xcd (256 KB strip).
// ---------------------------------------------------------------------------
__global__ __launch_bounds__(256) void gemm_out_mfma(
    const unsigned short* __restrict__ A, const unsigned short* __restrict__ Bt,
    float* __restrict__ C, int N, int K)
{
    __shared__ __align__(16) unsigned short As[2 * 128 * 32];
    __shared__ __align__(16) unsigned short Bs[2 * 128 * 32];

    const int id = blockIdx.x;            // 0..255
    const int n0 = (id & 7) * 128;
    const int m0 = (id >> 3) * 128;
    f32x4 acc[4][4];
    mfma_gemm_loop_db(A, Bt, As, Bs, m0, n0, K, acc);

    const int lane = threadIdx.x & 63;
    const int wave = threadIdx.x >> 6;
    const int quad = lane >> 4;
    const int lc   = lane & 15;
    const int wr   = (wave >> 1) * 64;
    const int wc   = (wave & 1) * 64;

#pragma unroll
    for (int mt = 0; mt < 4; mt++) {
        const int mb = m0 + wr + mt * 16 + quad * 4;
#pragma unroll
        for (int r = 0; r < 4; r++) {
            float* row = C + (size_t)(mb + r) * N + n0 + wc;
#pragma unroll
            for (int nb = 0; nb < 4; nb++)
                row[nb * 16 + lc] = acc[mt][nb][r];
        }
    }
}

// ---------------------------------------------------------------------------
// MFMA causal flash attention v7b (XCD-affine, balanced two-pass, dbuf K/V).
// Same as round 10/11 except Q is now (B,H,64,T) transposed: Q-fragments
// load with 16 scalar u16 loads per pass (amortized over 33 tiles).
// ---------------------------------------------------------------------------
__global__ __launch_bounds__(256, 2) void attn_mfma7(
    const unsigned short* __restrict__ Qt, const unsigned short* __restrict__ Kb,
    const unsigned short* __restrict__ Vtg, unsigned short* __restrict__ out)
{
    __shared__ __align__(16) unsigned short Ks[2][64 * 64];
    __shared__ __align__(16) unsigned short Vs[2][64 * 64];
    __shared__ __align__(16) unsigned short Ps[4][16 * 72];

    const int tid  = threadIdx.x;
    const int lane = tid & 63;
    const int wave = tid >> 6;           // 0..3
    const int quad = lane >> 4;
    const int lc   = lane & 15;
    const int rsw  = lc & 7;

    const int id   = blockIdx.x;             // 0..511
    const int slot = id >> 3;                // 0..63
    const int bh   = (id & 7) + 8 * (slot & 3);   // 4 heads per XCD
    const int xb   = slot >> 2;              // 0..15

    const size_t headK = (size_t)bh * T_SEQ * HDIM;   // K: (BH,T,64)
    const size_t headV = (size_t)bh * HDIM * T_SEQ;   // Qt,Vt: (BH,64,T)
    const int b = bh >> 4;
    const int h = bh & 15;

    const int c0   = wave * 2;
    const int krow = lane >> 3;
    const int d8sw = (lane & 7) ^ krow;
    unsigned short* pw = Ps[wave];

#pragma unroll
    for (int pass = 0; pass < 2; pass++) {
        const int qb = pass ? (31 - xb) : xb;
        const int t0 = qb * 64;
        const int n_tiles = qb + 1;

        // Q fragments from transposed layout: [qrow=lc][k=quad*8+j]
        s16x8 qf0, qf1;
        {
            const unsigned short* qp = Qt + headV + (size_t)(t0 + wave * 16 + lc);
#pragma unroll
            for (int j = 0; j < 8; j++) {
                qf0[j] = (short)qp[(size_t)(quad * 8 + j) * T_SEQ];
                qf1[j] = (short)qp[(size_t)(32 + quad * 8 + j) * T_SEQ];
            }
        }

        f32x4 o[4];
        float m_i = -INFINITY, l_i = 0.f;
#pragma unroll
        for (int db = 0; db < 4; db++)
            o[db] = (f32x4){0.f, 0.f, 0.f, 0.f};

        auto stage = [&](int s0, int buf) {
            const unsigned short* gk0 = Kb  + headK + (size_t)(s0 + c0 * 8 + krow) * HDIM + d8sw * 8;
            const unsigned short* gk1 = Kb  + headK + (size_t)(s0 + c0 * 8 + 8 + krow) * HDIM + d8sw * 8;
            const unsigned short* gv0 = Vtg + headV + (size_t)(c0 * 8 + krow) * T_SEQ + s0 + d8sw * 8;
            const unsigned short* gv1 = Vtg + headV + (size_t)(c0 * 8 + 8 + krow) * T_SEQ + s0 + d8sw * 8;
            __builtin_amdgcn_global_load_lds((GUI*)gk0, (LUI*)(Ks[buf] + c0 * 512 + lane * 8), 16, 0, 0);
            __builtin_amdgcn_global_load_lds((GUI*)gk1, (LUI*)(Ks[buf] + (c0 + 1) * 512 + lane * 8), 16, 0, 0);
            __builtin_amdgcn_global_load_lds((GUI*)gv0, (LUI*)(Vs[buf] + c0 * 512 + lane * 8), 16, 0, 0);
            __builtin_amdgcn_global_load_lds((GUI*)gv1, (LUI*)(Vs[buf] + (c0 + 1) * 512 + lane * 8), 16, 0, 0);
        };

        __syncthreads();
        stage(0, 0);

        for (int tile = 0; tile < n_tiles; ++tile) {
            const int s0 = tile * 64;
            const int buf = tile & 1;
            __syncthreads();
            if (tile + 1 < n_tiles) stage(s0 + 64, buf ^ 1);

            const unsigned short* ks = Ks[buf];
            const unsigned short* vs = Vs[buf];

            f32x4 st[4];
#pragma unroll
            for (int kb = 0; kb < 4; kb++) {
                const s16x8 ka0 = *(const s16x8*)&ks[(kb * 16 + lc) * 64 + ((quad ^ rsw) * 8)];
                const s16x8 ka1 = *(const s16x8*)&ks[(kb * 16 + lc) * 64 + (((4 + quad) ^ rsw) * 8)];
                f32x4 z = (f32x4){0.f, 0.f, 0.f, 0.f};
                z = __builtin_amdgcn_mfma_f32_16x16x32_bf16(ka0, qf0, z, 0, 0, 0);
                z = __builtin_amdgcn_mfma_f32_16x16x32_bf16(ka1, qf1, z, 0, 0, 0);
                st[kb] = z;
            }

            s16x8 va[4][2];
#pragma unroll
            for (int db = 0; db < 4; db++) {
                va[db][0] = *(const s16x8*)&vs[(db * 16 + lc) * 64 + ((quad ^ rsw) * 8)];
                va[db][1] = *(const s16x8*)&vs[(db * 16 + lc) * 64 + (((4 + quad) ^ rsw) * 8)];
            }

            if (tile == n_tiles - 1) {
                const int qrow = t0 + wave * 16 + lc;
#pragma unroll
                for (int kb = 0; kb < 4; kb++) {
                    const int key = s0 + kb * 16 + quad * 4;
#pragma unroll
                    for (int r = 0; r < 4; r++)
                        if (key + r > qrow) st[kb][r] = -INFINITY;
                }
            }

            float mt = st[0][0];
#pragma unroll
            for (int kb = 0; kb < 4; kb++)
#pragma unroll
                for (int r = 0; r < 4; r++) mt = fmaxf(mt, st[kb][r]);
            mt = fmaxf(mt, __shfl_xor(mt, 16));
            mt = fmaxf(mt, __shfl_xor(mt, 32));
            const float mn = fmaxf(m_i, mt);
            const float alpha = __builtin_amdgcn_exp2f(m_i - mn);
            m_i = mn;
            float rs = 0.f;
#pragma unroll
            for (int kb = 0; kb < 4; kb++)
#pragma unroll
                for (int r = 0; r < 4; r++) {
                    const float p = __builtin_amdgcn_exp2f(st[kb][r] - mn);
                    st[kb][r] = p;
                    rs += p;
                }
            rs += __shfl_xor(rs, 16);
            rs += __shfl_xor(rs, 32);
            l_i = l_i * alpha + rs;
#pragma unroll
            for (int db = 0; db < 4; db++) {
                o[db][0] *= alpha; o[db][1] *= alpha;
                o[db][2] *= alpha; o[db][3] *= alpha;
            }
#pragma unroll
            for (int kb = 0; kb < 4; kb++) {
                u32x2 pk;
                pk[0] = f2bf_pack2(st[kb][0], st[kb][1]);
                pk[1] = f2bf_pack2(st[kb][2], st[kb][3]);
                *(u32x2*)&pw[lc * 72 + kb * 16 + quad * 4] = pk;
            }
            const s16x8 pb0 = *(const s16x8*)&pw[lc * 72 + quad * 8];
            const s16x8 pb1 = *(const s16x8*)&pw[lc * 72 + 32 + quad * 8];
#pragma unroll
            for (int db = 0; db < 4; db++) {
                o[db] = __builtin_amdgcn_mfma_f32_16x16x32_bf16(va[db][0], pb0, o[db], 0, 0, 0);
                o[db] = __builtin_amdgcn_mfma_f32_16x16x32_bf16(va[db][1], pb1, o[db], 0, 0, 0);
            }
        }

        {
            const float inv_l = 1.f / l_i;
            const int t = t0 + wave * 16 + lc;
            unsigned short* orow = out + (size_t)(b * T_SEQ + t) * DMODEL + h * HDIM + quad * 4;
#pragma unroll
            for (int db = 0; db < 4; db++) {
                u32x2 pk;
                pk[0] = f2bf_pack2(o[db][0] * inv_l, o[db][1] * inv_l);
                pk[1] = f2bf_pack2(o[db][2] * inv_l, o[db][3] * inv_l);
                *(u32x2*)(orow + db * 16) = pk;
            }
        }
    }
}

// ---------------------------------------------------------------------------
extern "C" void kernel_launch(void* const* d_in, const int* in_sizes, int n_in,
                              void* d_out, int out_size, void* d_ws, size_t ws_size,
                              hipStream_t stream)
{
    const float* x    = (const float*)d_in[0];   // (B,T,D) fp32
    const float* Wqkv = (const float*)d_in[1];   // (D,3D) fp32
    const float* Wout = (const float*)d_in[2];   // (D,D) fp32
    // d_in[3] attn_mask: causal triu(k=1), applied analytically.

    float* out = (float*)d_out;

    char* ws = (char*)d_ws;
    unsigned short* attnb  = (unsigned short*)(ws);               // (B,T,D) bf16, 8 MB
    unsigned short* Qt     = (unsigned short*)(ws + (8u  << 20)); // (B,H,64,T) bf16
    unsigned short* Kb     = (unsigned short*)(ws + (16u << 20)); // (B,H,T,64) bf16
    unsigned short* Vt     = (unsigned short*)(ws + (24u << 20)); // (B,H,64,T) bf16
    unsigned short* xbuf   = (unsigned short*)(ws + (32u << 20)); // (M,K) bf16
    unsigned short* Wqkv_t = (unsigned short*)(ws + (40u << 20)); // (3D,D) bf16
    unsigned short* Wout_t = (unsigned short*)(ws + (46u << 20)); // (D,D) bf16
    float*          ropeT  = (float*)        (ws + (48u << 20)); // [32][2048] float2, 512 KB

    // 0) fused prep: convert x, transpose weights, build RoPE table (tabT)
    prep_fused<<<dim3(3328), 256, 0, stream>>>(x, Wqkv, Wout, xbuf, Wqkv_t, Wout_t,
                                               (float2*)ropeT);

    // 1) QKV MFMA GEMM (dbuf, XCD-affine) + RoPE + scale + pack (Q,V transposed)
    gemm_qkv_rope_mfma<<<dim3(768), 256, 0, stream>>>(xbuf, Wqkv_t, ropeT, Qt, Kb, Vt);

    // 2) MFMA causal flash attention v7b (XCD-affine) -> attnb (B,T,D) bf16
    attn_mfma7<<<dim3(512), 256, 0, stream>>>(Qt, Kb, Vt, attnb);

    // 3) out = attnb @ Wout  (fp32 out, dbuf, XCD-affine)
    gemm_out_mfma<<<dim3(256), 256, 0, stream>>>(attnb, Wout_t, out, DMODEL, DMODEL);
}

// Round 14
// 195.325 us; speedup vs baseline: 1.0680x; 1.0680x over previous
//
#include <hip/hip_runtime.h>
#include <math.h>

#define BATCH   2
#define T_SEQ   2048
#define DMODEL  1024
#define NHEAD   16
#define HDIM    64

typedef short s16x8 __attribute__((ext_vector_type(8)));
typedef unsigned short u16x8 __attribute__((ext_vector_type(8)));
typedef unsigned short u16x4 __attribute__((ext_vector_type(4)));
typedef unsigned int u32x2 __attribute__((ext_vector_type(2)));
typedef float f32x4 __attribute__((ext_vector_type(4)));

typedef const unsigned int __attribute__((address_space(1))) GUI;
typedef unsigned int __attribute__((address_space(3))) LUI;

// fp32 -> bf16 round-to-nearest-even (bit pattern)
static __device__ __forceinline__ unsigned short f2bf(float f) {
    unsigned int u = __float_as_uint(f);
    u += 0x7fffu + ((u >> 16) & 1u);
    return (unsigned short)(u >> 16);
}

// two fp32 -> packed bf16x2 (round-half-up) via one v_perm_b32
static __device__ __forceinline__ unsigned int f2bf_pack2(float a, float b) {
    const unsigned int ua = __float_as_uint(a) + 0x8000u;
    const unsigned int ub = __float_as_uint(b) + 0x8000u;
    return __builtin_amdgcn_perm(ub, ua, 0x07060302u);
}

// ---------------------------------------------------------------------------
// Fused prep: blocks 0..2047 convert x -> bf16; 2048..2815 transpose Wqkv;
// 2816..3071 transpose Wout; 3072..3327 build RoPE cos/sin table
// tab[t][d2] = (cos(t*f_d2), sin(t*f_d2)), f_d2 = 10000^(-d2/32).
// ---------------------------------------------------------------------------
__global__ __launch_bounds__(256) void prep_fused(
    const float* __restrict__ x, const float* __restrict__ Wqkv,
    const float* __restrict__ Wout,
    unsigned short* __restrict__ xb, unsigned short* __restrict__ Wqkv_t,
    unsigned short* __restrict__ Wout_t, float2* __restrict__ rope_tab)
{
    __shared__ unsigned short tile[64][68];
    const int bid = blockIdx.x;
    const int tid = threadIdx.x;

    if (bid < 2048) {
        const int i = bid * 256 + tid;
        const float4 a = ((const float4*)x)[2 * i];
        const float4 b = ((const float4*)x)[2 * i + 1];
        u16x8 r;
        r[0] = f2bf(a.x); r[1] = f2bf(a.y); r[2] = f2bf(a.z); r[3] = f2bf(a.w);
        r[4] = f2bf(b.x); r[5] = f2bf(b.y); r[6] = f2bf(b.z); r[7] = f2bf(b.w);
        ((u16x8*)xb)[i] = r;
        return;
    }
    if (bid >= 3072) {
        // RoPE table: 65536 entries = 256 blocks x 256 threads
        const int idx = (bid - 3072) * 256 + tid;
        const int t = idx >> 5;
        const int d2 = idx & 31;
        const float inv_freq = exp2f(-(float)d2 * 0.41524101186092029f); // log2(1e4)/32
        float s, c;
        sincosf((float)t * inv_freq, &s, &c);
        rope_tab[idx] = make_float2(c, s);
        return;
    }

    const float* src;
    unsigned short* dst;
    int R, C, bx, by;
    if (bid < 2816) {
        const int id = bid - 2048;
        src = Wqkv; dst = Wqkv_t; R = DMODEL; C = 3 * DMODEL;
        bx = id % 48; by = id / 48;
    } else {
        const int id = bid - 2816;
        src = Wout; dst = Wout_t; R = DMODEL; C = DMODEL;
        bx = id % 16; by = id / 16;
    }
    const int tc0 = bx * 64;
    const int tr0 = by * 64;
    const int tx = tid & 63;
    const int ty = tid >> 6;
#pragma unroll
    for (int i = 0; i < 16; i++) {
        const int rr = i * 4 + ty;
        tile[tx][rr] = f2bf(src[(size_t)(tr0 + rr) * C + tc0 + tx]);
    }
    __syncthreads();
#pragma unroll
    for (int i = 0; i < 16; i++) {
        const int cc = i * 4 + ty;
        dst[(size_t)(tc0 + cc) * R + tr0 + tx] = tile[cc][tx];
    }
}

// ---------------------------------------------------------------------------
// Shared MFMA GEMM main loop, DOUBLE-BUFFERED, one barrier per K-slice.
// ---------------------------------------------------------------------------
__device__ __forceinline__ void mfma_gemm_loop_db(
    const unsigned short* __restrict__ A, const unsigned short* __restrict__ Bt,
    unsigned short* As, unsigned short* Bs,
    int m0, int n0, int K, f32x4 acc[4][4])
{
    const int tid  = threadIdx.x;
    const int wave = tid >> 6;
    const int lane = tid & 63;
    const int quad = lane >> 4;
    const int lc   = lane & 15;
    const int wr   = (wave >> 1) * 64;
    const int wc   = (wave & 1) * 64;

    const int c0    = wave * 2;
    const int srow0 = c0 * 16 + (lane >> 2);
    const int scol  = (lane & 3) * 8;

#pragma unroll
    for (int i = 0; i < 4; i++)
#pragma unroll
        for (int j = 0; j < 4; j++)
            acc[i][j] = (f32x4){0.f, 0.f, 0.f, 0.f};

    auto stage = [&](int kt, int buf) {
        const unsigned short* ga0 = A + (size_t)(m0 + srow0) * K + kt + scol;
        const unsigned short* ga1 = A + (size_t)(m0 + srow0 + 16) * K + kt + scol;
        const unsigned short* gb0 = Bt + (size_t)(n0 + srow0) * K + kt + scol;
        const unsigned short* gb1 = Bt + (size_t)(n0 + srow0 + 16) * K + kt + scol;
        unsigned short* as = As + buf * 4096;
        unsigned short* bs = Bs + buf * 4096;
        __builtin_amdgcn_global_load_lds((GUI*)ga0, (LUI*)(as + c0 * 512 + lane * 8), 16, 0, 0);
        __builtin_amdgcn_global_load_lds((GUI*)ga1, (LUI*)(as + (c0 + 1) * 512 + lane * 8), 16, 0, 0);
        __builtin_amdgcn_global_load_lds((GUI*)gb0, (LUI*)(bs + c0 * 512 + lane * 8), 16, 0, 0);
        __builtin_amdgcn_global_load_lds((GUI*)gb1, (LUI*)(bs + (c0 + 1) * 512 + lane * 8), 16, 0, 0);
    };

    stage(0, 0);
    const int nit = K >> 5;
    for (int it = 0; it < nit; ++it) {
        __syncthreads();
        if (it + 1 < nit) stage((it + 1) << 5, (it + 1) & 1);

        const unsigned short* as = As + (it & 1) * 4096;
        const unsigned short* bs = Bs + (it & 1) * 4096;
        s16x8 a[4], b[4];
#pragma unroll
        for (int mt = 0; mt < 4; mt++)
            a[mt] = *(const s16x8*)(as + (wr + mt * 16 + lc) * 32 + quad * 8);
#pragma unroll
        for (int nb = 0; nb < 4; nb++)
            b[nb] = *(const s16x8*)(bs + (wc + nb * 16 + lc) * 32 + quad * 8);
#pragma unroll
        for (int mt = 0; mt < 4; mt++)
#pragma unroll
            for (int nb = 0; nb < 4; nb++)
                acc[mt][nb] = __builtin_amdgcn_mfma_f32_16x16x32_bf16(a[mt], b[nb], acc[mt][nb], 0, 0, 0);
    }
}

// ---------------------------------------------------------------------------
// QKV GEMM (bf16 MFMA, dbuf) + RoPE (table lookup) + Q-scale + pack.
// 1-D grid 768, XCD-affine: xcd = id&7 owns n-blocks [3*xcd, 3*xcd+3);
// the 3 n-subs cycle innermost so each x m-tile is reused 3x back-to-back
// and the 768 KB weight strip stays L2-resident per XCD.
// ---------------------------------------------------------------------------
__global__ __launch_bounds__(256) void gemm_qkv_rope_mfma(
    const unsigned short* __restrict__ xb, const unsigned short* __restrict__ Wt,
    const float2* __restrict__ rope_tab,
    unsigned short* __restrict__ Qb, unsigned short* __restrict__ Kb,
    unsigned short* __restrict__ Vb)
{
    __shared__ __align__(16) unsigned short As[2 * 128 * 32];
    __shared__ __align__(16) unsigned short Bs[2 * 128 * 32];

    const int id  = blockIdx.x;               // 0..767
    const int s   = id >> 3;                  // 0..95
    const int n0  = ((id & 7) * 3 + (s % 3)) * 128;
    const int m0  = (s / 3) * 128;
    f32x4 acc[4][4];
    mfma_gemm_loop_db(xb, Wt, As, Bs, m0, n0, DMODEL, acc);

    const int lane = threadIdx.x & 63;
    const int wave = threadIdx.x >> 6;
    const int quad = lane >> 4;
    const int lc   = lane & 15;
    const int wr   = (wave >> 1) * 64;
    const int wc   = (wave & 1) * 64;

    const int n_base = n0 + wc;
    const int part = n_base >> 10;       // 0=q 1=k 2=v, uniform per block
    unsigned short* dst = (part == 0) ? Qb : (part == 1 ? Kb : Vb);
    const float scale = (part == 0) ? 0.125f * 1.4426950408889634f : 1.0f;

#pragma unroll
    for (int nb = 0; nb < 4; nb++) {
        const int n = n_base + nb * 16 + lc;
        const int h = (n >> 6) & 15;
        const int d = n & 63;
        if (part == 2) {
#pragma unroll
            for (int mt = 0; mt < 4; mt++) {
                const int mb = m0 + wr + mt * 16 + quad * 4;
                const int bb = mb >> 11, t = mb & 2047;
                u16x4 pk;
                pk[0] = f2bf(acc[mt][nb][0]); pk[1] = f2bf(acc[mt][nb][1]);
                pk[2] = f2bf(acc[mt][nb][2]); pk[3] = f2bf(acc[mt][nb][3]);
                *(u16x4*)&dst[((size_t)(bb * NHEAD + h) * HDIM + d) * T_SEQ + t] = pk;
            }
        } else {
            const size_t hb = (size_t)h * T_SEQ * HDIM + d;
            const int d2 = d >> 1;
            const float ssign = (lc & 1) ? 1.f : -1.f;
#pragma unroll
            for (int mt = 0; mt < 4; mt++) {
                const int mb = m0 + wr + mt * 16 + quad * 4;
#pragma unroll
                for (int r = 0; r < 4; r++) {
                    const float val = acc[mt][nb][r];
                    const float prt = __shfl_xor(val, 1);
                    const int m = mb + r;
                    const int bb = m >> 11, t = m & 2047;
                    const float2 sc = rope_tab[t * 32 + d2];   // (cos, sin)
                    const float res = fmaf(prt, ssign * sc.y, val * sc.x) * scale;
                    dst[(size_t)bb * NHEAD * T_SEQ * HDIM + hb + (size_t)t * HDIM] = f2bf(res);
                }
            }
        }
    }
}

// ---------------------------------------------------------------------------
// Out-proj GEMM (bf16 MFMA, dbuf): out[M,1024] fp32 = attnb x Wout_t^T.
// 1-D grid 256, XCD-affine: xcd = id&7 owns n-block xcd (256 KB strip).
// ---------------------------------------------------------------------------
__global__ __launch_bounds__(256) void gemm_out_mfma(
    const unsigned short* __restrict__ A, const unsigned short* __restrict__ Bt,
    float* __restrict__ C, int N, int K)
{
    __shared__ __align__(16) unsigned short As[2 * 128 * 32];
    __shared__ __align__(16) unsigned short Bs[2 * 128 * 32];

    const int id = blockIdx.x;            // 0..255
    const int n0 = (id & 7) * 128;
    const int m0 = (id >> 3) * 128;
    f32x4 acc[4][4];
    mfma_gemm_loop_db(A, Bt, As, Bs, m0, n0, K, acc);

    const int lane = threadIdx.x & 63;
    const int wave = threadIdx.x >> 6;
    const int quad = lane >> 4;
    const int lc   = lane & 15;
    const int wr   = (wave >> 1) * 64;
    const int wc   = (wave & 1) * 64;

#pragma unroll
    for (int mt = 0; mt < 4; mt++) {
        const int mb = m0 + wr + mt * 16 + quad * 4;
#pragma unroll
        for (int r = 0; r < 4; r++) {
            float* row = C + (size_t)(mb + r) * N + n0 + wc;
#pragma unroll
            for (int nb = 0; nb < 4; nb++)
                row[nb * 16 + lc] = acc[mt][nb][r];
        }
    }
}

// ---------------------------------------------------------------------------
// MFMA causal flash attention v7 (XCD-affine, balanced two-pass, dbuf K/V).
// ---------------------------------------------------------------------------
__global__ __launch_bounds__(256, 2) void attn_mfma7(
    const unsigned short* __restrict__ Qb, const unsigned short* __restrict__ Kb,
    const unsigned short* __restrict__ Vtg, unsigned short* __restrict__ out)
{
    __shared__ __align__(16) unsigned short Ks[2][64 * 64];
    __shared__ __align__(16) unsigned short Vs[2][64 * 64];
    __shared__ __align__(16) unsigned short Ps[4][16 * 72];

    const int tid  = threadIdx.x;
    const int lane = tid & 63;
    const int wave = tid >> 6;           // 0..3
    const int quad = lane >> 4;
    const int lc   = lane & 15;
    const int rsw  = lc & 7;

    const int id   = blockIdx.x;             // 0..511
    const int slot = id >> 3;                // 0..63
    const int bh   = (id & 7) + 8 * (slot & 3);   // 4 heads per XCD
    const int xb   = slot >> 2;              // 0..15

    const size_t headK = (size_t)bh * T_SEQ * HDIM;   // Q,K: (BH,T,64)
    const size_t headV = (size_t)bh * HDIM * T_SEQ;   // Vt:  (BH,64,T)
    const int b = bh >> 4;
    const int h = bh & 15;

    const int c0   = wave * 2;
    const int krow = lane >> 3;
    const int d8sw = (lane & 7) ^ krow;
    unsigned short* pw = Ps[wave];

#pragma unroll
    for (int pass = 0; pass < 2; pass++) {
        const int qb = pass ? (31 - xb) : xb;
        const int t0 = qb * 64;
        const int n_tiles = qb + 1;

        s16x8 qf0, qf1;
        {
            const size_t qrow = headK + (size_t)(t0 + wave * 16 + lc) * HDIM;
            qf0 = *(const s16x8*)(Qb + qrow + quad * 8);
            qf1 = *(const s16x8*)(Qb + qrow + 32 + quad * 8);
        }

        f32x4 o[4];
        float m_i = -INFINITY, l_i = 0.f;
#pragma unroll
        for (int db = 0; db < 4; db++)
            o[db] = (f32x4){0.f, 0.f, 0.f, 0.f};

        auto stage = [&](int s0, int buf) {
            const unsigned short* gk0 = Kb  + headK + (size_t)(s0 + c0 * 8 + krow) * HDIM + d8sw * 8;
            const unsigned short* gk1 = Kb  + headK + (size_t)(s0 + c0 * 8 + 8 + krow) * HDIM + d8sw * 8;
            const unsigned short* gv0 = Vtg + headV + (size_t)(c0 * 8 + krow) * T_SEQ + s0 + d8sw * 8;
            const unsigned short* gv1 = Vtg + headV + (size_t)(c0 * 8 + 8 + krow) * T_SEQ + s0 + d8sw * 8;
            __builtin_amdgcn_global_load_lds((GUI*)gk0, (LUI*)(Ks[buf] + c0 * 512 + lane * 8), 16, 0, 0);
            __builtin_amdgcn_global_load_lds((GUI*)gk1, (LUI*)(Ks[buf] + (c0 + 1) * 512 + lane * 8), 16, 0, 0);
            __builtin_amdgcn_global_load_lds((GUI*)gv0, (LUI*)(Vs[buf] + c0 * 512 + lane * 8), 16, 0, 0);
            __builtin_amdgcn_global_load_lds((GUI*)gv1, (LUI*)(Vs[buf] + (c0 + 1) * 512 + lane * 8), 16, 0, 0);
        };

        __syncthreads();
        stage(0, 0);

        for (int tile = 0; tile < n_tiles; ++tile) {
            const int s0 = tile * 64;
            const int buf = tile & 1;
            __syncthreads();
            if (tile + 1 < n_tiles) stage(s0 + 64, buf ^ 1);

            const unsigned short* ks = Ks[buf];
            const unsigned short* vs = Vs[buf];

            f32x4 st[4];
#pragma unroll
            for (int kb = 0; kb < 4; kb++) {
                const s16x8 ka0 = *(const s16x8*)&ks[(kb * 16 + lc) * 64 + ((quad ^ rsw) * 8)];
                const s16x8 ka1 = *(const s16x8*)&ks[(kb * 16 + lc) * 64 + (((4 + quad) ^ rsw) * 8)];
                f32x4 z = (f32x4){0.f, 0.f, 0.f, 0.f};
                z = __builtin_amdgcn_mfma_f32_16x16x32_bf16(ka0, qf0, z, 0, 0, 0);
                z = __builtin_amdgcn_mfma_f32_16x16x32_bf16(ka1, qf1, z, 0, 0, 0);
                st[kb] = z;
            }

            s16x8 va[4][2];
#pragma unroll
            for (int db = 0; db < 4; db++) {
                va[db][0] = *(const s16x8*)&vs[(db * 16 + lc) * 64 + ((quad ^ rsw) * 8)];
                va[db][1] = *(const s16x8*)&vs[(db * 16 + lc) * 64 + (((4 + quad) ^ rsw) * 8)];
            }

            if (tile == n_tiles - 1) {
                const int qrow = t0 + wave * 16 + lc;
#pragma unroll
                for (int kb = 0; kb < 4; kb++) {
                    const int key = s0 + kb * 16 + quad * 4;
#pragma unroll
                    for (int r = 0; r < 4; r++)
                        if (key + r > qrow) st[kb][r] = -INFINITY;
                }
            }

            float mt = st[0][0];
#pragma unroll
            for (int kb = 0; kb < 4; kb++)
#pragma unroll
                for (int r = 0; r < 4; r++) mt = fmaxf(mt, st[kb][r]);
            mt = fmaxf(mt, __shfl_xor(mt, 16));
            mt = fmaxf(mt, __shfl_xor(mt, 32));
            const float mn = fmaxf(m_i, mt);
            const float alpha = __builtin_amdgcn_exp2f(m_i - mn);
            m_i = mn;
            float rs = 0.f;
#pragma unroll
            for (int kb = 0; kb < 4; kb++)
#pragma unroll
                for (int r = 0; r < 4; r++) {
                    const float p = __builtin_amdgcn_exp2f(st[kb][r] - mn);
                    st[kb][r] = p;
                    rs += p;
                }
            rs += __shfl_xor(rs, 16);
            rs += __shfl_xor(rs, 32);
            l_i = l_i * alpha + rs;
#pragma unroll
            for (int db = 0; db < 4; db++) {
                o[db][0] *= alpha; o[db][1] *= alpha;
                o[db][2] *= alpha; o[db][3] *= alpha;
            }
#pragma unroll
            for (int kb = 0; kb < 4; kb++) {
                u32x2 pk;
                pk[0] = f2bf_pack2(st[kb][0], st[kb][1]);
                pk[1] = f2bf_pack2(st[kb][2], st[kb][3]);
                *(u32x2*)&pw[lc * 72 + kb * 16 + quad * 4] = pk;
            }
            const s16x8 pb0 = *(const s16x8*)&pw[lc * 72 + quad * 8];
            const s16x8 pb1 = *(const s16x8*)&pw[lc * 72 + 32 + quad * 8];
#pragma unroll
            for (int db = 0; db < 4; db++) {
                o[db] = __builtin_amdgcn_mfma_f32_16x16x32_bf16(va[db][0], pb0, o[db], 0, 0, 0);
                o[db] = __builtin_amdgcn_mfma_f32_16x16x32_bf16(va[db][1], pb1, o[db], 0, 0, 0);
            }
        }

        {
            const float inv_l = 1.f / l_i;
            const int t = t0 + wave * 16 + lc;
            unsigned short* orow = out + (size_t)(b * T_SEQ + t) * DMODEL + h * HDIM + quad * 4;
#pragma unroll
            for (int db = 0; db < 4; db++) {
                u32x2 pk;
                pk[0] = f2bf_pack2(o[db][0] * inv_l, o[db][1] * inv_l);
                pk[1] = f2bf_pack2(o[db][2] * inv_l, o[db][3] * inv_l);
                *(u32x2*)(orow + db * 16) = pk;
            }
        }
    }
}

// ---------------------------------------------------------------------------
extern "C" void kernel_launch(void* const* d_in, const int* in_sizes, int n_in,
                              void* d_out, int out_size, void* d_ws, size_t ws_size,
                              hipStream_t stream)
{
    const float* x    = (const float*)d_in[0];   // (B,T,D) fp32
    const float* Wqkv = (const float*)d_in[1];   // (D,3D) fp32
    const float* Wout = (const float*)d_in[2];   // (D,D) fp32
    // d_in[3] attn_mask: causal triu(k=1), applied analytically.

    float* out = (float*)d_out;

    char* ws = (char*)d_ws;
    unsigned short* attnb  = (unsigned short*)(ws);               // (B,T,D) bf16, 8 MB
    unsigned short* Qb     = (unsigned short*)(ws + (8u  << 20)); // (B,H,T,64)
    unsigned short* Kb     = (unsigned short*)(ws + (16u << 20)); // (B,H,T,64)
    unsigned short* Vt     = (unsigned short*)(ws + (24u << 20)); // (B,H,64,T)
    unsigned short* xbuf   = (unsigned short*)(ws + (32u << 20)); // (M,K) bf16
    unsigned short* Wqkv_t = (unsigned short*)(ws + (40u << 20)); // (3D,D) bf16
    unsigned short* Wout_t = (unsigned short*)(ws + (46u << 20)); // (D,D) bf16
    float2*         ropeT  = (float2*)       (ws + (48u << 20)); // 2048x32 float2, 512 KB

    // 0) fused prep: convert x, transpose weights, build RoPE table
    prep_fused<<<dim3(3328), 256, 0, stream>>>(x, Wqkv, Wout, xbuf, Wqkv_t, Wout_t, ropeT);

    // 1) QKV MFMA GEMM (dbuf, XCD-affine) + RoPE table + scale + pack
    gemm_qkv_rope_mfma<<<dim3(768), 256, 0, stream>>>(xbuf, Wqkv_t, ropeT, Qb, Kb, Vt);

    // 2) MFMA causal flash attention v7 (XCD-affine) -> attnb (B,T,D) bf16
    attn_mfma7<<<dim3(512), 256, 0, stream>>>(Qb, Kb, Vt, attnb);

    // 3) out = attnb @ Wout  (fp32 out, dbuf, XCD-affine)
    gemm_out_mfma<<<dim3(256), 256, 0, stream>>>(attnb, Wout_t, out, DMODEL, DMODEL);
}